// Round 9
// baseline (349.508 us; speedup 1.0000x reference)
//
#include <hip/hip_runtime.h>
#include <hip/hip_bf16.h>

typedef __attribute__((ext_vector_type(16))) float floatx16;
typedef __attribute__((ext_vector_type(8))) short shortx8;

#define NB   16
#define CIN  256
#define COUT 256
#define KW   3
#define LL   4096
#define LLP  4098   // LL + 2 guard rows (zeros) per b in xt
#define NR   5
#define QK   768    // CIN*KW
#define NP   65536  // NB*LL

static __device__ __forceinline__ unsigned short bf16bits(float f) {
    __hip_bfloat16 h = __float2bfloat16(f);
    return __builtin_bit_cast(unsigned short, h);
}

// async global->LDS, 16B per lane, LDS dest = wave-uniform base + lane*16
static __device__ __forceinline__ void gload16(const void* g, void* l) {
    __builtin_amdgcn_global_load_lds(
        (const __attribute__((address_space(1))) void*)g,
        (__attribute__((address_space(3))) void*)l, 16, 0, 0);
}

// ---------------- K1: transpose + weight prep (wb, wc) + guard-row zeroing ----------------
// wc layout: [kh*16 + r][cin] bf16, r<5 -> cw[(cin*3+kh)*5 + r], r>=5 -> 0 (pad rows).
__global__ void k_tfr(const float* __restrict__ x, const float* __restrict__ bk,
                      const float* __restrict__ cw,
                      __hip_bfloat16* __restrict__ wb, __hip_bfloat16* __restrict__ wc,
                      __hip_bfloat16* __restrict__ xt) {
    __shared__ float t[64][65];
    int l0 = blockIdx.x * 64, b = blockIdx.y;
    int bid = blockIdx.y * 64 + blockIdx.x;           // 0..1023
    int tid = threadIdx.x;
    int r16 = tid >> 4, q16 = tid & 15;

    // --- wprep: wb[m*QK + k*256 + cin], m = (o>>4)*80 + r*16 + (o&15) ---
    #pragma unroll
    for (int jj = 0; jj < 4; ++jj) {
        int i = bid * 1024 + jj * 256 + tid;
        if (i < NR * COUT * QK) {
            int m = i / QK, qq = i % QK;
            int o = (m / 80) * 16 + (m & 15);
            int r = (m % 80) / 16;
            int k = qq >> 8, cin = qq & 255;
            wb[i] = __float2bfloat16(bk[((r * COUT + o) * CIN + cin) * KW + k]);
        }
    }
    // --- wc prep: 48 rows x 256 cins ---
    if (bid < 48) {
        int row = bid, cin = tid;
        int kh = row >> 4, r = row & 15;
        float v = (r < NR) ? cw[(cin * 3 + kh) * NR + r] : 0.f;
        wc[row * 256 + cin] = __float2bfloat16(v);
    }
    // --- guard rows 0,1 of each b-slab = causal zeros ---
    {
        int i0 = bid * 256 + tid;
        if (i0 < NB * 2 * CIN) {
            int bb = i0 >> 9, rr = i0 & 511;
            xt[(size_t)bb * LLP * CIN + rr] = __float2bfloat16(0.f);
        }
    }

    // --- transpose x (B,Cin,L) fp32 -> xt (B, 2+L, Cin) bf16 ---
    for (int ch = 0; ch < 4; ++ch) {
        __syncthreads();
        #pragma unroll
        for (int pass = 0; pass < 4; ++pass) {
            int cin = pass * 16 + r16;
            float4 v = *(const float4*)&x[((size_t)(b * CIN + ch * 64 + cin)) * LL + l0 + q16 * 4];
            t[q16 * 4 + 0][cin] = v.x;
            t[q16 * 4 + 1][cin] = v.y;
            t[q16 * 4 + 2][cin] = v.z;
            t[q16 * 4 + 3][cin] = v.w;
        }
        __syncthreads();
        #pragma unroll
        for (int pass = 0; pass < 4; ++pass) {
            int lr = pass * 16 + r16;
            int c4 = q16 * 4;
            ushort4 u;
            u.x = bf16bits(t[lr][c4 + 0]);
            u.y = bf16bits(t[lr][c4 + 1]);
            u.z = bf16bits(t[lr][c4 + 2]);
            u.w = bf16bits(t[lr][c4 + 3]);
            *(ushort4*)&xt[((size_t)(b * LLP + 2 + l0 + lr)) * CIN + ch * 64 + c4] = u;
        }
    }
}

// ---------------- K2: conv + controller + softmax + mixture, 32x32x16 MFMA, wave tile 96x128 ----------------
// GEMM M=96(80 conv + 16 ctrl) x N=65536 x K=768, y-split over 16 COUT groups.
// Block: 512 thr / 8 waves, N_block=1024, each wave 96x128 (3 Mfrag x 4 Nfrag of 32).
// Wave-tile N 64->128 cuts LDS reads/FLOP by 30% (reads/FLOP ~ 1/Mw + 1/Nw).
// 16 K-phases of 16 cins, mfma_f32_32x32x16_bf16 (K=16, A: m=lane&31,k=(lane>>5)*8+j;
// C/D: col=lane&31, row=(reg&3)+8*(reg>>2)+4*(lane>>5) [guide m74/m101]).
// LDS slabs, [k-half][row] contiguous layout (stride-1 b128 = conflict-free, no swizzle):
//   X: 2 halves x 1026 rows = 2052 chunks (32.8 KB); W': 2 x 288 strips = 576 chunks (9.2 KB).
// Double-buffered: 84.1 KB static -> 1 block/CU, 8 waves = 2/SIMD (same TLP as r8).
// Schedule: r2-proven drain (r7 measured counted-vmcnt +-1%).
// Lane ownership: lane holds ALL 5 rules for its 8 output rows (olo = {0..3,8..11}+4*half),
// ctrl logits: half0 regs 8..11 = rules 0..3, half1 reg 8 = rule 4 -> tiny LDS exchange.
#define XCH   2052    // X chunks per slab
#define WCH2  576     // W' chunks per slab
#define WBASE 4104    // chunk index of W' region (2*XCH)
__global__ __launch_bounds__(512, 2)
void k_conv(const __hip_bfloat16* __restrict__ xt, const __hip_bfloat16* __restrict__ wb,
            const __hip_bfloat16* __restrict__ wc, const float* __restrict__ bias,
            const float* __restrict__ cbv, float* __restrict__ out) {
    __shared__ __align__(16) short lds[(2 * XCH + 2 * WCH2) * 8];  // 84,096 B
    __shared__ float bs[80];                                       // 320 B

    int g = blockIdx.x;                   // 1024 blocks
    int pt = ((g >> 7) << 3) | (g & 7);   // XCD swizzle: g=128a+8y+xl -> pt=8a+xl (bijective)
    int y  = (g >> 3) & 15;
    int p0 = pt * 1024;
    int m0 = y * 80, o0 = y * 16;
    int b = p0 >> 12, l0 = p0 & (LL - 1);
    int tid = threadIdx.x;
    int lane = tid & 63, wn = tid >> 6;
    int col = lane & 31, half = lane >> 5;

    const __hip_bfloat16* xb = xt + (size_t)b * (LLP * CIN);

    if (tid < 80) bs[tid] = bias[(tid >> 4) * COUT + o0 + (tid & 15)];
    float cbl[NR];
    #pragma unroll
    for (int n = 0; n < NR; ++n) cbl[n] = cbv[n];

    // ---- X staging: chunk c -> (h = c/1026, row = c%1026); src = (l0+row)*CIN + h*8 (+ph*16) ----
    const int xbase[5] = {0, 512, 1024, 1536, 1540};   // call 4 overlaps 1540..2051 (rewrite-same)
    int xoff[5];
    #pragma unroll
    for (int j = 0; j < 5; ++j) {
        int c = xbase[j] + tid;
        int h = c / 1026, row = c % 1026;
        xoff[j] = (l0 + row) * CIN + h * 8;
    }
    // ---- W' staging: chunk c -> (h = c/288, s = c%288), s = kh*96 + mp ----
    const __hip_bfloat16* wptr[2];
    #pragma unroll
    for (int j = 0; j < 2; ++j) {
        int c = (j == 0) ? tid : 64 + tid;             // call 1 overlaps 64..575
        int h = c / 288, s = c % 288;
        int kh = s / 96, mp = s - kh * 96;
        wptr[j] = (mp < 80) ? wb + ((m0 + mp) * QK + kh * 256 + h * 8)
                            : wc + ((kh * 16 + mp - 80) * 256 + h * 8);
    }

    // ---- per-lane LDS read bases (shorts within a slab) ----
    int bbS = (half * 1026 + wn * 128 + col) * 8;      // + (nf*32 + kh)*8 const
    int aaS = (half * 288 + col) * 8;                  // + (kh*96 + mf*32)*8 const

    floatx16 acc[3][4];
    #pragma unroll
    for (int mf = 0; mf < 3; ++mf)
        #pragma unroll
        for (int nf = 0; nf < 4; ++nf)
            acc[mf][nf] = (floatx16)(0.f);

    auto stage = [&](int buf, int ph) {    // exactly 7 gload16 per wave
        short* BX = &lds[buf * XCH * 8];
        const __hip_bfloat16* xp = xb + ph * 16;
        #pragma unroll
        for (int j = 0; j < 5; ++j)
            gload16(xp + xoff[j], BX + (xbase[j] + wn * 64) * 8);
        short* BW = &lds[(WBASE + buf * WCH2) * 8];
        gload16(wptr[0] + ph * 16, BW + (wn * 64) * 8);
        gload16(wptr[1] + ph * 16, BW + (64 + wn * 64) * 8);
    };

    auto compute = [&](int buf) {
        const short* X = &lds[buf * XCH * 8];
        const short* W = &lds[(WBASE + buf * WCH2) * 8];
        #pragma unroll
        for (int kh = 0; kh < 3; ++kh) {
            shortx8 af[3], bf[4];
            #pragma unroll
            for (int mf = 0; mf < 3; ++mf)
                af[mf] = *(const shortx8*)&W[aaS + (kh * 96 + mf * 32) * 8];
            #pragma unroll
            for (int nf = 0; nf < 4; ++nf)
                bf[nf] = *(const shortx8*)&X[bbS + (nf * 32 + kh) * 8];
            #pragma unroll
            for (int mf = 0; mf < 3; ++mf)
                #pragma unroll
                for (int nf = 0; nf < 4; ++nf)
                    acc[mf][nf] = __builtin_amdgcn_mfma_f32_32x32x16_bf16(
                        af[mf], bf[nf], acc[mf][nf], 0, 0, 0);
        }
    };

    // ---- drain-style double-buffer (r2-proven) ----
    stage(0, 0);
    __syncthreads();
    #pragma unroll
    for (int ph = 0; ph < 16; ++ph) {
        if (ph < 15) stage((ph + 1) & 1, ph + 1);
        compute(ph & 1);
        __syncthreads();
    }

    // ---- epilogue 1: exchange ctrl logits via LDS (stride 6, 2 lanes/bank = free) ----
    float* scf = (float*)lds;
    int sbase = wn * 128 * 6;
    #pragma unroll
    for (int nf = 0; nf < 4; ++nf) {
        int pp = sbase + (nf * 32 + col) * 6;
        if (half == 0) {
            scf[pp + 0] = acc[2][nf][8];
            scf[pp + 1] = acc[2][nf][9];
            scf[pp + 2] = acc[2][nf][10];
            scf[pp + 3] = acc[2][nf][11];
        } else {
            scf[pp + 4] = acc[2][nf][8];   // crow 20 = ctrl row 4 = rule 4
        }
    }
    __syncthreads();

    // ---- epilogue 2: softmax + mixture + store ----
    // lane's 8 output rows: olo(j) = (j&3) + 8*(j>>2) + 4*half, j=0..7.
    // rule r values: r0=acc[0][nf][j], r1=acc[0][nf][j+8], r2=acc[1][nf][j],
    //                r3=acc[1][nf][j+8], r4=acc[2][nf][j].
    #pragma unroll
    for (int nf = 0; nf < 4; ++nf) {
        int colp = wn * 128 + nf * 32 + col;
        int pp = sbase + (nf * 32 + col) * 6;
        float l2[NR];
        #pragma unroll
        for (int n = 0; n < NR; ++n) l2[n] = scf[pp + n] + cbl[n];
        float mx = l2[0];
        #pragma unroll
        for (int n = 1; n < NR; ++n) mx = fmaxf(mx, l2[n]);
        float e[NR], s = 0.f;
        #pragma unroll
        for (int n = 0; n < NR; ++n) { e[n] = __expf(l2[n] - mx); s += e[n]; }
        float inv = 1.f / s;
        float f0 = e[0] * inv, f1 = e[1] * inv, f2 = e[2] * inv, f3 = e[3] * inv, f4 = e[4] * inv;
        #pragma unroll
        for (int j = 0; j < 8; ++j) {
            int olo = (j & 3) + 8 * (j >> 2) + 4 * half;
            float v = f0 * (acc[0][nf][j]     + bs[ 0 + olo])
                    + f1 * (acc[0][nf][j + 8] + bs[16 + olo])
                    + f2 * (acc[1][nf][j]     + bs[32 + olo])
                    + f3 * (acc[1][nf][j + 8] + bs[48 + olo])
                    + f4 * (acc[2][nf][j]     + bs[64 + olo]);
            out[((size_t)(b * COUT + o0 + olo)) * LL + l0 + colp] = v;
        }
    }
}

extern "C" void kernel_launch(void* const* d_in, const int* in_sizes, int n_in,
                              void* d_out, int out_size, void* d_ws, size_t ws_size,
                              hipStream_t stream) {
    const float* x  = (const float*)d_in[0];
    const float* bk = (const float*)d_in[1];
    const float* bb = (const float*)d_in[2];
    const float* cw = (const float*)d_in[3];
    const float* cb = (const float*)d_in[4];
    float* out = (float*)d_out;

    char* ws = (char*)d_ws;
    __hip_bfloat16* xt = (__hip_bfloat16*)ws;                          // 16*4098*256*2 = 33,570,816 B
    __hip_bfloat16* wb = (__hip_bfloat16*)(ws + 33570816);             //  1,966,080 B
    __hip_bfloat16* wc = (__hip_bfloat16*)(ws + 33570816 + 1966080);   //     24,576 B

    k_tfr<<<dim3(LL / 64, NB), dim3(256), 0, stream>>>(x, bk, cw, wb, wc, xt);
    k_conv<<<dim3(NP / 1024 * (COUT / 16)), dim3(512), 0, stream>>>(xt, wb, wc, bb, cb, out);
}

// Round 10
// 335.944 us; speedup vs baseline: 1.0404x; 1.0404x over previous
//
#include <hip/hip_runtime.h>
#include <hip/hip_bf16.h>

typedef __attribute__((ext_vector_type(16))) float floatx16;
typedef __attribute__((ext_vector_type(8))) short shortx8;

#define NB   16
#define CIN  256
#define COUT 256
#define KW   3
#define LL   4096
#define LLP  4098   // LL + 2 guard rows (zeros) per b in xt
#define NR   5
#define QK   768    // CIN*KW
#define NP   65536  // NB*LL

static __device__ __forceinline__ unsigned short bf16bits(float f) {
    __hip_bfloat16 h = __float2bfloat16(f);
    return __builtin_bit_cast(unsigned short, h);
}

// async global->LDS, 16B per lane, LDS dest = wave-uniform base + lane*16
static __device__ __forceinline__ void gload16(const void* g, void* l) {
    __builtin_amdgcn_global_load_lds(
        (const __attribute__((address_space(1))) void*)g,
        (__attribute__((address_space(3))) void*)l, 16, 0, 0);
}

// ---------------- K1: transpose + weight prep (wb, wc) + guard-row zeroing ----------------
// wc layout: [kh*16 + r][cin] bf16, r<5 -> cw[(cin*3+kh)*5 + r], r>=5 -> 0 (pad rows).
__global__ void k_tfr(const float* __restrict__ x, const float* __restrict__ bk,
                      const float* __restrict__ cw,
                      __hip_bfloat16* __restrict__ wb, __hip_bfloat16* __restrict__ wc,
                      __hip_bfloat16* __restrict__ xt) {
    __shared__ float t[64][65];
    int l0 = blockIdx.x * 64, b = blockIdx.y;
    int bid = blockIdx.y * 64 + blockIdx.x;           // 0..1023
    int tid = threadIdx.x;
    int r16 = tid >> 4, q16 = tid & 15;

    // --- wprep: wb[m*QK + k*256 + cin], m = (o>>4)*80 + r*16 + (o&15) ---
    #pragma unroll
    for (int jj = 0; jj < 4; ++jj) {
        int i = bid * 1024 + jj * 256 + tid;
        if (i < NR * COUT * QK) {
            int m = i / QK, qq = i % QK;
            int o = (m / 80) * 16 + (m & 15);
            int r = (m % 80) / 16;
            int k = qq >> 8, cin = qq & 255;
            wb[i] = __float2bfloat16(bk[((r * COUT + o) * CIN + cin) * KW + k]);
        }
    }
    // --- wc prep: 48 rows x 256 cins ---
    if (bid < 48) {
        int row = bid, cin = tid;
        int kh = row >> 4, r = row & 15;
        float v = (r < NR) ? cw[(cin * 3 + kh) * NR + r] : 0.f;
        wc[row * 256 + cin] = __float2bfloat16(v);
    }
    // --- guard rows 0,1 of each b-slab = causal zeros ---
    {
        int i0 = bid * 256 + tid;
        if (i0 < NB * 2 * CIN) {
            int bb = i0 >> 9, rr = i0 & 511;
            xt[(size_t)bb * LLP * CIN + rr] = __float2bfloat16(0.f);
        }
    }

    // --- transpose x (B,Cin,L) fp32 -> xt (B, 2+L, Cin) bf16 ---
    for (int ch = 0; ch < 4; ++ch) {
        __syncthreads();
        #pragma unroll
        for (int pass = 0; pass < 4; ++pass) {
            int cin = pass * 16 + r16;
            float4 v = *(const float4*)&x[((size_t)(b * CIN + ch * 64 + cin)) * LL + l0 + q16 * 4];
            t[q16 * 4 + 0][cin] = v.x;
            t[q16 * 4 + 1][cin] = v.y;
            t[q16 * 4 + 2][cin] = v.z;
            t[q16 * 4 + 3][cin] = v.w;
        }
        __syncthreads();
        #pragma unroll
        for (int pass = 0; pass < 4; ++pass) {
            int lr = pass * 16 + r16;
            int c4 = q16 * 4;
            ushort4 u;
            u.x = bf16bits(t[lr][c4 + 0]);
            u.y = bf16bits(t[lr][c4 + 1]);
            u.z = bf16bits(t[lr][c4 + 2]);
            u.w = bf16bits(t[lr][c4 + 3]);
            *(ushort4*)&xt[((size_t)(b * LLP + 2 + l0 + lr)) * CIN + ch * 64 + c4] = u;
        }
    }
}

// ---------------- K2: conv + controller + softmax + mixture, 32x32x16 MFMA ----------------
// GEMM M=96 (80 conv + 16 ctrl) x N=65536 x K=768, y-split over 16 COUT groups.
// Block: 256 thr / 4 waves (1M x 4N), N_block=512; wave tile 96x128 (3 Mfrag x 4 Nfrag).
// r9 lesson: need >=2 independent barrier domains (blocks) per CU for m114 overlap ->
// keep LDS small via 16-cin phases: X slab = [h][row] 2x514 chunks (16.4 KB), W' slab
// [h][strip] 2x288 chunks (9.2 KB); double-buffered = 51.3 KB -> 2 blocks/CU.
// Layout is contiguous [h][row] -> frag reads are 2x512B contiguous segments = uniform
// 8 words/bank (conflict-free, NO swizzle); staging identity-linear (no pre-swizzle).
// Reads/FLOP: 7 KB per 12 MFMA-32 per wave-phase = 30% below r8 -> LDS floor ~34 us.
// Schedule: r2-proven drain (r7: counted-vmcnt was +-1%).
// Epilogue lane-map (verified r9, absmax ok): C/D col=lane&31, row=(reg&3)+8*(reg>>2)
// +4*half; lane's 8 rows olo(j)=(j&3)+8*(j>>2)+4*half; ctrl logits in mf2 regs 8..11
// (half0: rules 0-3) and reg 8 (half1: rule 4).
#define XSH   8224    // shorts per X slab (1028 chunks)
#define WSH   4608    // shorts per W' slab (576 chunks)
#define WOFFS 16448   // short offset of W' region (2*XSH)
__global__ __launch_bounds__(256, 2)
void k_conv(const __hip_bfloat16* __restrict__ xt, const __hip_bfloat16* __restrict__ wb,
            const __hip_bfloat16* __restrict__ wc, const float* __restrict__ bias,
            const float* __restrict__ cbv, float* __restrict__ out) {
    __shared__ __align__(16) short lds[2 * XSH + 2 * WSH];   // 51,328 B
    __shared__ float bs[80];                                 // 320 B

    int g = blockIdx.x;                   // 2048 blocks
    int pt = ((g >> 7) << 3) | (g & 7);   // XCD swizzle: g=128a+8y+xl -> pt=8a+xl (bijective)
    int y  = (g >> 3) & 15;
    int p0 = pt * 512;
    int m0 = y * 80, o0 = y * 16;
    int b = p0 >> 12, l0 = p0 & (LL - 1);
    int tid = threadIdx.x;
    int lane = tid & 63, wn = tid >> 6;
    int col = lane & 31, half = lane >> 5;

    const __hip_bfloat16* xb = xt + (size_t)b * (LLP * CIN);

    if (tid < 80) bs[tid] = bias[(tid >> 4) * COUT + o0 + (tid & 15)];
    float cbl[NR];
    #pragma unroll
    for (int n = 0; n < NR; ++n) cbl[n] = cbv[n];

    // ---- X staging: chunk c -> (h=c/514, row=c%514); src = (l0+row)*CIN + h*8 (+ph*16) ----
    const int xbase[5] = {0, 256, 512, 768, 772};   // call 4 covers 772..1027 (rewrite-same 772..1023)
    int xoff[5];
    #pragma unroll
    for (int j = 0; j < 5; ++j) {
        int c = xbase[j] + tid;
        int h = c / 514, row = c % 514;
        xoff[j] = (l0 + row) * CIN + h * 8;
    }
    // ---- W' staging: chunk c -> (h=c/288, s=c%288), s = kh*96 + mp ----
    const int wbase[3] = {0, 256, 320};             // call 2 covers 320..575 (rewrite-same 320..511)
    const __hip_bfloat16* wptr[3];
    #pragma unroll
    for (int j = 0; j < 3; ++j) {
        int c = wbase[j] + tid;
        int h = c / 288, s = c % 288;
        int kh = s / 96, mp = s - kh * 96;
        wptr[j] = (mp < 80) ? wb + ((m0 + mp) * QK + kh * 256 + h * 8)
                            : wc + ((kh * 16 + mp - 80) * 256 + h * 8);
    }

    // ---- per-lane LDS read bases (shorts within a slab) ----
    int bbS = (half * 514 + wn * 128 + col) * 8;    // + (nf*32 + kh)*8
    int aaS = (half * 288 + col) * 8;               // + (kh*96 + mf*32)*8

    floatx16 acc[3][4];
    #pragma unroll
    for (int mf = 0; mf < 3; ++mf)
        #pragma unroll
        for (int nf = 0; nf < 4; ++nf)
            acc[mf][nf] = (floatx16)(0.f);

    auto stage = [&](int buf, int ph) {    // exactly 8 gload16 per wave
        short* BX = &lds[buf * XSH];
        const __hip_bfloat16* xp = xb + ph * 16;
        #pragma unroll
        for (int j = 0; j < 5; ++j)
            gload16(xp + xoff[j], BX + (xbase[j] + wn * 64) * 8);
        short* BW = &lds[WOFFS + buf * WSH];
        #pragma unroll
        for (int j = 0; j < 3; ++j)
            gload16(wptr[j] + ph * 16, BW + (wbase[j] + wn * 64) * 8);
    };

    auto compute = [&](int buf) {
        const short* X = &lds[buf * XSH];
        const short* W = &lds[WOFFS + buf * WSH];
        #pragma unroll
        for (int kh = 0; kh < 3; ++kh) {
            shortx8 af[3], bf[4];
            #pragma unroll
            for (int mf = 0; mf < 3; ++mf)
                af[mf] = *(const shortx8*)&W[aaS + (kh * 96 + mf * 32) * 8];
            #pragma unroll
            for (int nf = 0; nf < 4; ++nf)
                bf[nf] = *(const shortx8*)&X[bbS + (nf * 32 + kh) * 8];
            #pragma unroll
            for (int mf = 0; mf < 3; ++mf)
                #pragma unroll
                for (int nf = 0; nf < 4; ++nf)
                    acc[mf][nf] = __builtin_amdgcn_mfma_f32_32x32x16_bf16(
                        af[mf], bf[nf], acc[mf][nf], 0, 0, 0);
        }
    };

    // ---- drain-style double-buffer (r2-proven) ----
    stage(0, 0);
    __syncthreads();
    #pragma unroll
    for (int ph = 0; ph < 16; ++ph) {
        if (ph < 15) stage((ph + 1) & 1, ph + 1);
        compute(ph & 1);
        __syncthreads();
    }

    // ---- epilogue 1: exchange ctrl logits via LDS (stride 6 floats) ----
    float* scf = (float*)lds;
    int sbase = wn * 128 * 6;
    #pragma unroll
    for (int nf = 0; nf < 4; ++nf) {
        int pp = sbase + (nf * 32 + col) * 6;
        if (half == 0) {
            scf[pp + 0] = acc[2][nf][8];
            scf[pp + 1] = acc[2][nf][9];
            scf[pp + 2] = acc[2][nf][10];
            scf[pp + 3] = acc[2][nf][11];
        } else {
            scf[pp + 4] = acc[2][nf][8];   // ctrl row 4 = rule 4
        }
    }
    __syncthreads();

    // ---- epilogue 2: softmax + mixture + store ----
    #pragma unroll
    for (int nf = 0; nf < 4; ++nf) {
        int colp = wn * 128 + nf * 32 + col;
        int pp = sbase + (nf * 32 + col) * 6;
        float l2[NR];
        #pragma unroll
        for (int n = 0; n < NR; ++n) l2[n] = scf[pp + n] + cbl[n];
        float mx = l2[0];
        #pragma unroll
        for (int n = 1; n < NR; ++n) mx = fmaxf(mx, l2[n]);
        float e[NR], s = 0.f;
        #pragma unroll
        for (int n = 0; n < NR; ++n) { e[n] = __expf(l2[n] - mx); s += e[n]; }
        float inv = 1.f / s;
        float f0 = e[0] * inv, f1 = e[1] * inv, f2 = e[2] * inv, f3 = e[3] * inv, f4 = e[4] * inv;
        #pragma unroll
        for (int j = 0; j < 8; ++j) {
            int olo = (j & 3) + 8 * (j >> 2) + 4 * half;
            float v = f0 * (acc[0][nf][j]     + bs[ 0 + olo])
                    + f1 * (acc[0][nf][j + 8] + bs[16 + olo])
                    + f2 * (acc[1][nf][j]     + bs[32 + olo])
                    + f3 * (acc[1][nf][j + 8] + bs[48 + olo])
                    + f4 * (acc[2][nf][j]     + bs[64 + olo]);
            out[((size_t)(b * COUT + o0 + olo)) * LL + l0 + colp] = v;
        }
    }
}

extern "C" void kernel_launch(void* const* d_in, const int* in_sizes, int n_in,
                              void* d_out, int out_size, void* d_ws, size_t ws_size,
                              hipStream_t stream) {
    const float* x  = (const float*)d_in[0];
    const float* bk = (const float*)d_in[1];
    const float* bb = (const float*)d_in[2];
    const float* cw = (const float*)d_in[3];
    const float* cb = (const float*)d_in[4];
    float* out = (float*)d_out;

    char* ws = (char*)d_ws;
    __hip_bfloat16* xt = (__hip_bfloat16*)ws;                          // 16*4098*256*2 = 33,570,816 B
    __hip_bfloat16* wb = (__hip_bfloat16*)(ws + 33570816);             //  1,966,080 B
    __hip_bfloat16* wc = (__hip_bfloat16*)(ws + 33570816 + 1966080);   //     24,576 B

    k_tfr<<<dim3(LL / 64, NB), dim3(256), 0, stream>>>(x, bk, cw, wb, wc, xt);
    k_conv<<<dim3(NP / 512 * (COUT / 16)), dim3(256), 0, stream>>>(xt, wb, wc, bb, cb, out);
}